// Round 1
// baseline (428.776 us; speedup 1.0000x reference)
//
#include <hip/hip_runtime.h>
#include <hip/hip_bf16.h>

#define M_LEN 1024
#define BATCH 16384

#define BM 128
#define BN 128
#define BK 64
#define THREADS 256

typedef __attribute__((ext_vector_type(8))) short bf16x8;
typedef __attribute__((ext_vector_type(4))) float f32x4;
typedef unsigned short ushort_t;

// ---------------- helpers ----------------

// fp32 -> bf16 RNE
__device__ __forceinline__ ushort_t bf16_rne(float f) {
    unsigned u = __float_as_uint(f);
    unsigned r = u + 0x7FFFu + ((u >> 16) & 1u);
    return (ushort_t)(r >> 16);
}

__device__ __forceinline__ float bf16_to_f(ushort_t u) {
    return __uint_as_float(((unsigned)u) << 16);
}

// pack two fp32 -> two bf16 (RTZ) in one v_perm_b32 (fallback kernel only)
__device__ __forceinline__ unsigned pack2(float lo, float hi) {
    return __builtin_amdgcn_perm(__float_as_uint(hi), __float_as_uint(lo), 0x07060302u);
}

// async global->LDS, 16B per lane. LDS dest is wave-uniform base + lane*16.
__device__ __forceinline__ void gload_lds16(const void* g, void* l) {
    __builtin_amdgcn_global_load_lds(
        (const __attribute__((address_space(1))) unsigned int*)g,
        (__attribute__((address_space(3))) unsigned int*)l,
        16, 0, 0);
}

// non-temporal 16B load: builtin requires native ext_vector_type, not HIP structs
__device__ __forceinline__ float4 ntload4(const float4* p) {
    f32x4 v = __builtin_nontemporal_load((const f32x4*)p);
    return make_float4(v.x, v.y, v.z, v.w);
}

// ---------------- pass 1: fp32 -> bf16 conversion + zero-row flags ----------------
// blocks 0..16383: block b, wave m converts mod_m row b -> Ab[(4b+m)*1024 ...]
//                  and writes zf[4b+m] = (row is all +-0.0) ? 1 : 0
// blocks 16384..16639: wave w converts W row (blk-16384)*4+w -> Wb
// UNCHANGED this round: its counters will surface in the next top-5 once
// gemm_fused drops below it, giving data for a targeted fix.
__global__ __launch_bounds__(THREADS) void convert_pass(
    const float* __restrict__ mod0, const float* __restrict__ mod1,
    const float* __restrict__ mod2, const float* __restrict__ mod3,
    const float* __restrict__ W,
    ushort_t* __restrict__ Ab, ushort_t* __restrict__ Wb, int* __restrict__ zf)
{
    const int blk  = blockIdx.x;
    const int wave = threadIdx.x >> 6;
    const int lane = threadIdx.x & 63;

    if (blk < BATCH) {
        const int b = blk, m = wave;
        const float* mp = (m == 0) ? mod0 : (m == 1) ? mod1 : (m == 2) ? mod2 : mod3;
        const float4* row = (const float4*)(mp + (size_t)b * M_LEN);
        ushort_t* dst = Ab + ((size_t)b * 4 + m) * M_LEN;
        unsigned orr = 0u;
        #pragma unroll
        for (int j = 0; j < 4; ++j) {
            float4 v = ntload4(&row[j * 64 + lane]);
            orr |= (__float_as_uint(v.x) | __float_as_uint(v.y) |
                    __float_as_uint(v.z) | __float_as_uint(v.w)) << 1;  // drop signs
            ushort4 o;
            o.x = bf16_rne(v.x); o.y = bf16_rne(v.y);
            o.z = bf16_rne(v.z); o.w = bf16_rne(v.w);
            ((ushort4*)dst)[j * 64 + lane] = o;
        }
        const int nz = __any(orr != 0u);
        if (lane == 0) zf[b * 4 + m] = nz ? 0 : 1;
    } else {
        const int r = (blk - BATCH) * 4 + wave;
        const float4* row = (const float4*)(W + (size_t)r * M_LEN);
        ushort_t* dst = Wb + (size_t)r * M_LEN;
        #pragma unroll
        for (int j = 0; j < 4; ++j) {
            float4 v = row[j * 64 + lane];
            ushort4 o;
            o.x = bf16_rne(v.x); o.y = bf16_rne(v.y);
            o.z = bf16_rne(v.z); o.w = bf16_rne(v.w);
            ((ushort4*)dst)[j * 64 + lane] = o;
        }
    }
}

// ---------------- pass 2: bf16 MFMA GEMM + in-lane softmax epilogue ----------------
// Round-2 changes vs previous version:
//  (1) 2-phase double-buffered K-loop (T3-minimum): STAGE(t+1) issued before
//      COMPUTE(t); single raw s_barrier per K-tile with lgkmcnt(0)+vmcnt(0)
//      drained AFTER the MFMAs, so tile t+1's HBM latency hides under tile t's
//      compute. (Old loop drained vmcnt(0) at a barrier BEFORE compute: zero
//      overlap, fully exposed load latency -> MfmaUtil 31%.)
//  (2) T1 bijective XCD swizzle: 1-D grid of 4096, bid%8 = XCD gets 512
//      contiguous work-ids (64 row-panels x 8 col-blocks, col-fastest) so each
//      A' panel is fetched once per XCD L2 instead of 8x (FETCH 585 MB -> ~200).
__global__ __launch_bounds__(THREADS) void gemm_fused(
    const ushort_t* __restrict__ Ab, const ushort_t* __restrict__ Wb,
    const int* __restrict__ zf, float* __restrict__ out)
{
    __shared__ __align__(16) ushort_t As[2][BM * BK];   // 2 x 16 KB
    __shared__ __align__(16) ushort_t Bs[2][BN * BK];   // 2 x 16 KB
    __shared__ float scalerS[BM / 4];

    const int t    = threadIdx.x;
    const int lane = t & 63;
    const int wave = t >> 6;
    const int quad = lane >> 4;
    const int ln15 = lane & 15;
    const int wm   = wave >> 1;
    const int wn   = wave & 1;

    // T1: XCD-aware remap. 4096 blocks, 8 XCDs, 4096 % 8 == 0 -> bijective.
    const int bid  = blockIdx.x;
    const int wid  = (bid & 7) * 512 + (bid >> 3);
    const int colb = wid & 7;
    const int rowb = wid >> 3;
    const int row0 = rowb * BM;
    const int col0 = colb * BN;

    // staging: lane covers row r = wave*32 + q*8 + (lane>>3),
    // physical LDS slot = lane&7, global chunk = (lane&7)^(r&7)
    const int rloc = (lane >> 3);
    const int c    = (lane & 7) ^ rloc;
    const ushort_t* aPtr[4];
    const ushort_t* bPtr[4];
    #pragma unroll
    for (int q = 0; q < 4; ++q) {
        const int r = wave * 32 + q * 8 + rloc;
        aPtr[q] = Ab + (size_t)(row0 + r) * M_LEN + c * 8;
        bPtr[q] = Wb + (size_t)(col0 + r) * M_LEN + c * 8;
    }

    // prologue: stage tile 0 into buf 0 as early as possible
    #pragma unroll
    for (int q = 0; q < 4; ++q) {
        gload_lds16(aPtr[q], &As[0][(wave * 4 + q) * 512]);
        gload_lds16(bPtr[q], &Bs[0][(wave * 4 + q) * 512]);
        aPtr[q] += BK;
        bPtr[q] += BK;
    }

    if (t < 32) {
        const int4 f = ((const int4*)zf)[rowb * 32 + t];
        const int z = f.x + f.y + f.z + f.w;
        scalerS[t] = (z > 0) ? (float)(z + 1) : 1.0f;
    }

    f32x4 acc[4][4];
    #pragma unroll
    for (int i = 0; i < 4; ++i)
        #pragma unroll
        for (int j = 0; j < 4; ++j)
            acc[i][j] = (f32x4){0.f, 0.f, 0.f, 0.f};

    const unsigned slotB   = (unsigned)(quad ^ (ln15 & 7));
    const unsigned aRowOff = (unsigned)((wm * 64 + ln15) * 64);
    const unsigned bRowOff = (unsigned)((wn * 64 + ln15) * 64);

    // tile 0 resident before first ds_read
    asm volatile("s_waitcnt vmcnt(0)" ::: "memory");
    __builtin_amdgcn_s_barrier();

    for (int kt = 0; kt < 15; ++kt) {
        const int cur = kt & 1;
        const int nxt = cur ^ 1;
        // issue next tile's loads BEFORE computing current tile
        #pragma unroll
        for (int q = 0; q < 4; ++q) {
            gload_lds16(aPtr[q], &As[nxt][(wave * 4 + q) * 512]);
            gload_lds16(bPtr[q], &Bs[nxt][(wave * 4 + q) * 512]);
            aPtr[q] += BK;
            bPtr[q] += BK;
        }
        // compute current tile
        #pragma unroll
        for (int ks = 0; ks < 2; ++ks) {
            const unsigned slot8 = (slotB ^ (unsigned)(ks * 4)) * 8u;
            bf16x8 af[4], bfr[4];
            #pragma unroll
            for (int i = 0; i < 4; ++i)
                af[i] = *(const bf16x8*)(&As[cur][aRowOff + i * 1024 + slot8]);
            #pragma unroll
            for (int j = 0; j < 4; ++j)
                bfr[j] = *(const bf16x8*)(&Bs[cur][bRowOff + j * 1024 + slot8]);
            #pragma unroll
            for (int i = 0; i < 4; ++i)
                #pragma unroll
                for (int j = 0; j < 4; ++j)
                    acc[i][j] = __builtin_amdgcn_mfma_f32_16x16x32_bf16(
                        af[i], bfr[j], acc[i][j], 0, 0, 0);
        }
        // drain AFTER compute: own ds_reads of buf cur done (safe to overwrite
        // next iter), next tile's gload_lds landed (safe to read after barrier)
        asm volatile("s_waitcnt lgkmcnt(0)" ::: "memory");
        asm volatile("s_waitcnt vmcnt(0)" ::: "memory");
        __builtin_amdgcn_s_barrier();
    }

    // final tile (kt = 15, buf 1), no prefetch
    #pragma unroll
    for (int ks = 0; ks < 2; ++ks) {
        const unsigned slot8 = (slotB ^ (unsigned)(ks * 4)) * 8u;
        bf16x8 af[4], bfr[4];
        #pragma unroll
        for (int i = 0; i < 4; ++i)
            af[i] = *(const bf16x8*)(&As[1][aRowOff + i * 1024 + slot8]);
        #pragma unroll
        for (int j = 0; j < 4; ++j)
            bfr[j] = *(const bf16x8*)(&Bs[1][bRowOff + j * 1024 + slot8]);
        #pragma unroll
        for (int i = 0; i < 4; ++i)
            #pragma unroll
            for (int j = 0; j < 4; ++j)
                acc[i][j] = __builtin_amdgcn_mfma_f32_16x16x32_bf16(
                    af[i], bfr[j], acc[i][j], 0, 0, 0);
    }

    // epilogue: acc[i][j] components = scores of modalities 0..3 at one (b,k).
    // x comes from Ab (bf16, same values the GEMM used) — L2-hot after T1 swizzle.
    #pragma unroll
    for (int i = 0; i < 4; ++i) {
        const int bl = wm * 16 + i * 4 + quad;
        const int b  = rowb * 32 + bl;
        const float scal = scalerS[bl];
        const ushort_t* xr = Ab + (size_t)b * 4 * M_LEN;   // row 4b (modality 0)
        #pragma unroll
        for (int j = 0; j < 4; ++j) {
            const int k = col0 + wn * 64 + j * 16 + ln15;
            const float x0 = bf16_to_f(xr[k]);
            const float x1 = bf16_to_f(xr[M_LEN + k]);
            const float x2 = bf16_to_f(xr[2 * M_LEN + k]);
            const float x3 = bf16_to_f(xr[3 * M_LEN + k]);
            const f32x4 s = acc[i][j];
            const float mx = fmaxf(fmaxf(s.x, s.y), fmaxf(s.z, s.w));
            const float e0 = __expf(s.x - mx);
            const float e1 = __expf(s.y - mx);
            const float e2 = __expf(s.z - mx);
            const float e3 = __expf(s.w - mx);
            const float num = e0 * x0 + e1 * x1 + e2 * x2 + e3 * x3;
            const float v = num * scal / (e0 + e1 + e2 + e3);
            __builtin_nontemporal_store(v, &out[(size_t)b * M_LEN + k]);
        }
    }
}

// ---------------- fallback: round-1 single fused kernel (used if ws too small) ----
__global__ __launch_bounds__(THREADS) void fused_modal_attn(
    const float* __restrict__ mod0, const float* __restrict__ mod1,
    const float* __restrict__ mod2, const float* __restrict__ mod3,
    const float* __restrict__ W, float* __restrict__ out)
{
    __shared__ __align__(16) unsigned short As[BM * BK];
    __shared__ __align__(16) unsigned short Bs[BN * BK];
    __shared__ unsigned rowOr[BM];
    __shared__ float scalerS[BM / 4];

    const int t    = threadIdx.x;
    const int lane = t & 63;
    const int wave = t >> 6;
    const int quad = lane >> 4;
    const int ln15 = lane & 15;
    const int wm   = wave >> 1;
    const int wn   = wave & 1;

    const int colb = blockIdx.x;
    const int rowb = blockIdx.y;
    const int row0 = rowb * BM;
    const int col0 = colb * BN;

    if (t < BM) rowOr[t] = 0u;

    const int sr  = t >> 3;
    const int scl = t & 7;

    const float* ap[4];
    const float* bp[4];
    unsigned ldsOff[4];
    unsigned orAcc[4] = {0u, 0u, 0u, 0u};
    #pragma unroll
    for (int j = 0; j < 4; ++j) {
        const int r  = j * 32 + sr;
        const int gr = row0 + r;
        const int b  = gr >> 2;
        const int m  = gr & 3;
        const float* mp = (m == 0) ? mod0 : (m == 1) ? mod1 : (m == 2) ? mod2 : mod3;
        ap[j] = mp + (size_t)b * M_LEN + scl * 8;
        bp[j] = W + (size_t)(col0 + r) * M_LEN + scl * 8;
        ldsOff[j] = (unsigned)(r * 64 + ((scl ^ (r & 7)) * 8));
    }

    f32x4 acc[4][4];
    #pragma unroll
    for (int i = 0; i < 4; ++i)
        #pragma unroll
        for (int j = 0; j < 4; ++j)
            acc[i][j] = (f32x4){0.f, 0.f, 0.f, 0.f};

    const unsigned slotB   = (unsigned)(quad ^ (ln15 & 7));
    const unsigned aRowOff = (unsigned)((wm * 64 + ln15) * 64);
    const unsigned bRowOff = (unsigned)((wn * 64 + ln15) * 64);

    for (int it = 0; it < 16; ++it) {
        __syncthreads();
        #pragma unroll
        for (int j = 0; j < 4; ++j) {
            const float4* pa = (const float4*)ap[j];
            const float4* pb = (const float4*)bp[j];
            float4 a0 = pa[0], a1 = pa[1];
            float4 b0 = pb[0], b1 = pb[1];
            ap[j] += BK; bp[j] += BK;

            unsigned pA0 = pack2(a0.x, a0.y), pA1 = pack2(a0.z, a0.w);
            unsigned pA2 = pack2(a1.x, a1.y), pA3 = pack2(a1.z, a1.w);
            orAcc[j] |= (pA0 | pA1) | (pA2 | pA3);
            *(uint4*)(&As[ldsOff[j]]) = make_uint4(pA0, pA1, pA2, pA3);

            unsigned pB0 = pack2(b0.x, b0.y), pB1 = pack2(b0.z, b0.w);
            unsigned pB2 = pack2(b1.x, b1.y), pB3 = pack2(b1.z, b1.w);
            *(uint4*)(&Bs[ldsOff[j]]) = make_uint4(pB0, pB1, pB2, pB3);
        }
        __syncthreads();
        #pragma unroll
        for (int ks = 0; ks < 2; ++ks) {
            const unsigned slot8 = (slotB ^ (unsigned)(ks * 4)) * 8u;
            bf16x8 af[4], bfr[4];
            #pragma unroll
            for (int i = 0; i < 4; ++i)
                af[i] = *(const bf16x8*)(&As[aRowOff + i * 1024 + slot8]);
            #pragma unroll
            for (int j = 0; j < 4; ++j)
                bfr[j] = *(const bf16x8*)(&Bs[bRowOff + j * 1024 + slot8]);
            #pragma unroll
            for (int i = 0; i < 4; ++i)
                #pragma unroll
                for (int j = 0; j < 4; ++j)
                    acc[i][j] = __builtin_amdgcn_mfma_f32_16x16x32_bf16(
                        af[i], bfr[j], acc[i][j], 0, 0, 0);
        }
    }

    #pragma unroll
    for (int j = 0; j < 4; ++j)
        atomicOr(&rowOr[j * 32 + sr], orAcc[j]);
    __syncthreads();
    if (t < 32) {
        const int z = (rowOr[4 * t + 0] == 0u) + (rowOr[4 * t + 1] == 0u)
                    + (rowOr[4 * t + 2] == 0u) + (rowOr[4 * t + 3] == 0u);
        scalerS[t] = (z > 0) ? (float)(z + 1) : 1.0f;
    }
    __syncthreads();

    #pragma unroll
    for (int i = 0; i < 4; ++i) {
        const int bl = wm * 16 + i * 4 + quad;
        const int b  = rowb * 32 + bl;
        const float scal = scalerS[bl];
        #pragma unroll
        for (int j = 0; j < 4; ++j) {
            const int k = col0 + wn * 64 + j * 16 + ln15;
            const size_t off = (size_t)b * M_LEN + k;
            const float x0 = mod0[off], x1 = mod1[off];
            const float x2 = mod2[off], x3 = mod3[off];
            const f32x4 s = acc[i][j];
            const float mx = fmaxf(fmaxf(s.x, s.y), fmaxf(s.z, s.w));
            const float e0 = __expf(s.x - mx);
            const float e1 = __expf(s.y - mx);
            const float e2 = __expf(s.z - mx);
            const float e3 = __expf(s.w - mx);
            const float num = e0 * x0 + e1 * x1 + e2 * x2 + e3 * x3;
            out[off] = num * scal / (e0 + e1 + e2 + e3);
        }
    }
}

// ---------------- launch ----------------
extern "C" void kernel_launch(void* const* d_in, const int* in_sizes, int n_in,
                              void* d_out, int out_size, void* d_ws, size_t ws_size,
                              hipStream_t stream) {
    const float* mod0 = (const float*)d_in[0];
    const float* mod1 = (const float*)d_in[1];
    const float* mod2 = (const float*)d_in[2];
    const float* mod3 = (const float*)d_in[3];
    const float* W    = (const float*)d_in[4];
    float* out = (float*)d_out;

    // workspace layout: A' bf16 (128 MiB) | W bf16 (2 MiB) | zf int[65536] (256 KiB)
    const size_t abBytes = (size_t)4 * BATCH * M_LEN * sizeof(ushort_t);
    const size_t wbBytes = (size_t)M_LEN * M_LEN * sizeof(ushort_t);
    const size_t zfBytes = (size_t)4 * BATCH * sizeof(int);
    const size_t need = abBytes + wbBytes + zfBytes;

    if (ws_size >= need) {
        ushort_t* Ab = (ushort_t*)d_ws;
        ushort_t* Wb = (ushort_t*)((char*)d_ws + abBytes);
        int*      zfp = (int*)((char*)d_ws + abBytes + wbBytes);

        convert_pass<<<dim3(BATCH + M_LEN / 4), dim3(THREADS), 0, stream>>>(
            mod0, mod1, mod2, mod3, W, Ab, Wb, zfp);

        // 1-D grid: T1 XCD swizzle happens inside the kernel
        gemm_fused<<<dim3((M_LEN / BN) * ((4 * BATCH) / BM)), dim3(THREADS), 0, stream>>>(
            Ab, Wb, zfp, out);
    } else {
        dim3 grid(M_LEN / BN, (4 * BATCH) / BM);
        fused_modal_attn<<<grid, dim3(THREADS), 0, stream>>>(
            mod0, mod1, mod2, mod3, W, out);
    }
}